// Round 6
// baseline (492.287 us; speedup 1.0000x reference)
//
#include <hip/hip_runtime.h>
#include <hip/hip_cooperative_groups.h>
#include <cstddef>

namespace cg = cooperative_groups;

// Problem constants
#define NB 16
#define NVOX 128
#define NPT 1920
#define NPAIRS 32768   // 16 b * 16 tz * 16 ty * 8 x-pairs

// ---------------------------------------------------------------------------
// Shared-memory overlay. SMemA (tail): qs overlaid on h3's first 2048 floats
// (qs dead after stage1, h3 written only after). SMemA = 40,580 B,
// SMemB (tile worker) = 34,560 B -> union ~40.6 KB -> 4 blocks/CU,
// 16 waves/CU, cooperative grid of 4*256 = 1024 blocks.
// ---------------------------------------------------------------------------
struct SMemA {
    float x1s[1920];         // stage1 output, flat (64,30)
    float h3[7680];          // relu'd IN3 output; first 2048 double as qs
    float m4s[16], r4s[16];
    unsigned char lflags[2048];  // tz16 * ty16 * px8 pair flags
    int lcount;
};
struct SMemB {
    float2 raw[4312];        // 22x14x14 tile (34,496 B)
    int bc[16];              // per-batch active-pair counts
};
union __align__(16) SMem {
    SMemA a;
    SMemB b;
};

static __device__ __forceinline__ float2 f2(float a, float b) {
    float2 r; r.x = a; r.y = b; return r;
}

// Per-axis composed 7-tap coefficients (A^3 of zero-padded 3-tap average):
// interior [1,3,6,7,6,3,1]/27; boundary rows via cm1/c0/cp1 overrides.
__device__ __forceinline__ void coef(int g, float& cm1, float& c0, float& cp1)
{
    cm1 = (g == 1 || g == 127) ? 5.f : 6.f;
    c0  = (g == 0 || g == 127) ? 4.f : 7.f;
    cp1 = (g == 0 || g == 126) ? 5.f : 6.f;
}

// ---------------------------------------------------------------------------
// Zero the whole output at full write BW. grid 4096 x 256, float4 stores.
// Runs as its own kernel: the kernel boundary flushes caches, so the tile
// writers later never share a byte with the zero writers inside one kernel.
// ---------------------------------------------------------------------------
__global__ __launch_bounds__(256)
void zero_out(float4* __restrict__ out)
{
    int idx = blockIdx.x * 2048 + threadIdx.x;
    #pragma unroll
    for (int i = 0; i < 8; ++i)
        out[idx + i * 256] = make_float4(0.f, 0.f, 0.f, 0.f);
}

// ---------------------------------------------------------------------------
// Tail phase (device fn): stage1 GEMM + wave-per-channel MLP + point gen +
// active-pair compaction for ONE batch. 256 threads = 4 waves; each wave
// handles final channels w, w+4, w+8, w+12 (grouped convs never mix
// channels). All InstanceNorms via __shfl_xor butterflies in-register.
// Logic identical to the round-4 verified mega_tail (only thread count and
// the cc-loop mapping differ).
// ---------------------------------------------------------------------------
__device__ void tail_phase(SMem* S, int b, int t,
    const float* __restrict__ q, const float* __restrict__ w1,
    const float* __restrict__ b1, const float* __restrict__ qval,
    const float* __restrict__ w2, const float* __restrict__ b2,
    const float* __restrict__ w3, const float* __restrict__ b3,
    const float* __restrict__ w4, const float* __restrict__ b4,
    const float* __restrict__ w5, const float* __restrict__ b5,
    float4* __restrict__ pts, int* __restrict__ bcount,
    int* __restrict__ list)
{
    SMemA* A = &S->a;
    float* qs = A->h3;    // overlay: h3 not live until after stage1

    for (int u = t; u < 2048; u += 256) {
        qs[u] = q[b * 2048 + u];
        A->lflags[u] = 0;
    }
    if (t == 0) A->lcount = 0;
    __syncthreads();

    // stage1: x1[(o,l)] = b1[o] + sum_i w1[o,i] * q[b, i*8+l]
    for (int u = t; u < 1920; u += 256) {
        int o = u >> 3, l = u & 7;
        const float4* wr = (const float4*)(w1 + o * 256);
        float acc = 0.f;
        #pragma unroll 8
        for (int i4 = 0; i4 < 64; ++i4) {
            float4 w = wr[i4];
            int base = i4 * 32 + l;
            acc = fmaf(w.x, qs[base],      acc);
            acc = fmaf(w.y, qs[base + 8],  acc);
            acc = fmaf(w.z, qs[base + 16], acc);
            acc = fmaf(w.w, qs[base + 24], acc);
        }
        A->x1s[u] = b1[o] + acc;
    }
    __syncthreads();   // qs dead from here; h3 live

    const int l = t & 63;
    const int c1l = l >> 4;
    const int p16 = l & 15;
    const bool hasb = (p16 < 14);    // second element p16+16 < 30

    for (int cc = 0; cc < 4; ++cc) {
        const int c3 = (t >> 6) + 4 * cc;
        const int c1 = 4 * c3 + c1l;
        const float* xrow = A->x1s + c1 * 30;
        float a0 = xrow[p16];
        float a1 = hasb ? xrow[p16 + 16] : 0.f;

        // IN1 over 30 elems: butterfly within 16-lane channel group
        float s = a0 + a1, s2 = a0 * a0 + a1 * a1;
        #pragma unroll
        for (int m = 1; m <= 8; m <<= 1) {
            s  += __shfl_xor(s,  m);
            s2 += __shfl_xor(s2, m);
        }
        float mean = s * (1.f / 30.f);
        float var  = s2 * (1.f / 30.f) - mean * mean;
        float rstd = rsqrtf(var + 1e-5f);
        a0 = fmaxf((a0 - mean) * rstd, 0.f);
        a1 = fmaxf((a1 - mean) * rstd, 0.f);   // garbage if !hasb; masked

        // stage2: grouped conv 64->128
        const float w20 = w2[c1 * 2 + 0], w21 = w2[c1 * 2 + 1];
        const float b20 = b2[c1 * 2 + 0], b21 = b2[c1 * 2 + 1];
        float y00 = fmaf(a0, w20, b20), y01 = fmaf(a0, w21, b21);
        float y10 = fmaf(a1, w20, b20), y11 = fmaf(a1, w21, b21);

        // IN2 over 120 elems: butterfly within 32-lane half
        float u1 = y00 + y01 + (hasb ? (y10 + y11) : 0.f);
        float u2 = y00 * y00 + y01 * y01
                 + (hasb ? (y10 * y10 + y11 * y11) : 0.f);
        #pragma unroll
        for (int m = 1; m <= 16; m <<= 1) {
            u1 += __shfl_xor(u1, m);
            u2 += __shfl_xor(u2, m);
        }
        mean = u1 * (1.f / 120.f);
        var  = u2 * (1.f / 120.f) - mean * mean;
        rstd = rsqrtf(var + 1e-5f);
        y00 = fmaxf((y00 - mean) * rstd, 0.f);
        y01 = fmaxf((y01 - mean) * rstd, 0.f);
        y10 = fmaxf((y10 - mean) * rstd, 0.f);
        y11 = fmaxf((y11 - mean) * rstd, 0.f);

        // stage3: grouped conv 32->64
        const int c2 = c1 >> 1;
        const float w30 = w3[c2 * 2 + 0], w31 = w3[c2 * 2 + 1];
        const float b30 = b3[c2 * 2 + 0], b31 = b3[c2 * 2 + 1];
        float z000 = fmaf(y00, w30, b30), z001 = fmaf(y00, w31, b31);
        float z010 = fmaf(y01, w30, b30), z011 = fmaf(y01, w31, b31);
        float z100 = fmaf(y10, w30, b30), z101 = fmaf(y10, w31, b31);
        float z110 = fmaf(y11, w30, b30), z111 = fmaf(y11, w31, b31);

        // IN3 over 480 elems: full-wave butterfly
        float v1 = z000 + z001 + z010 + z011
                 + (hasb ? (z100 + z101 + z110 + z111) : 0.f);
        float v2 = z000 * z000 + z001 * z001 + z010 * z010 + z011 * z011
                 + (hasb ? (z100 * z100 + z101 * z101
                          + z110 * z110 + z111 * z111) : 0.f);
        #pragma unroll
        for (int m = 1; m <= 32; m <<= 1) {
            v1 += __shfl_xor(v1, m);
            v2 += __shfl_xor(v2, m);
        }
        mean = v1 * (1.f / 480.f);
        var  = v2 * (1.f / 480.f) - mean * mean;
        rstd = rsqrtf(var + 1e-5f);

        // normalize+relu -> h3; accumulate relu'd sums for IN4 stats
        // p(global in 480) = ((c2&1)*2 + j2)*120 + ((c1&1)*2 + j1)*30 + p1
        const int qb0 = (c1l >> 1) * 240;
        const int pb0 = (c1l & 1) * 60;
        float* hw = A->h3 + c3 * 480;
        float s4 = 0.f, q4 = 0.f;
        {
            float v;
            v = fmaxf((z000 - mean) * rstd, 0.f); hw[qb0 +       pb0 +      p16] = v; s4 += v; q4 += v * v;
            v = fmaxf((z001 - mean) * rstd, 0.f); hw[qb0 + 120 + pb0 +      p16] = v; s4 += v; q4 += v * v;
            v = fmaxf((z010 - mean) * rstd, 0.f); hw[qb0 +       pb0 + 30 + p16] = v; s4 += v; q4 += v * v;
            v = fmaxf((z011 - mean) * rstd, 0.f); hw[qb0 + 120 + pb0 + 30 + p16] = v; s4 += v; q4 += v * v;
            if (hasb) {
                v = fmaxf((z100 - mean) * rstd, 0.f); hw[qb0 +       pb0 +      p16 + 16] = v; s4 += v; q4 += v * v;
                v = fmaxf((z101 - mean) * rstd, 0.f); hw[qb0 + 120 + pb0 +      p16 + 16] = v; s4 += v; q4 += v * v;
                v = fmaxf((z110 - mean) * rstd, 0.f); hw[qb0 +       pb0 + 30 + p16 + 16] = v; s4 += v; q4 += v * v;
                v = fmaxf((z111 - mean) * rstd, 0.f); hw[qb0 + 120 + pb0 + 30 + p16 + 16] = v; s4 += v; q4 += v * v;
            }
        }
        #pragma unroll
        for (int m = 1; m <= 32; m <<= 1) {
            s4 += __shfl_xor(s4, m);
            q4 += __shfl_xor(q4, m);
        }
        if (l == 0) {
            // stage4 IN stats analytically:
            // x4[c, j*480+p] = h3[c,p]*w4[c*4+j] + b4[c*4+j]
            float sum4 = 0.f, sq4 = 0.f;
            #pragma unroll
            for (int j = 0; j < 4; ++j) {
                float ww = w4[c3 * 4 + j], bb = b4[c3 * 4 + j];
                sum4 += ww * s4 + 480.f * bb;
                sq4  += ww * ww * q4 + 2.f * ww * bb * s4 + 480.f * bb * bb;
            }
            float m4 = sum4 * (1.f / 1920.f);
            float var4 = sq4 * (1.f / 1920.f) - m4 * m4;
            A->m4s[c3] = m4; A->r4s[c3] = rsqrtf(var4 + 1e-5f);
        }
    }
    __syncthreads();

    // per-point: stage4 apply + stage5 einsum + tanh + emit + mark pairs
    for (int p = t; p < NPT; p += 256) {
        int j = p / 480;
        int pp = p - j * 480;
        float a0e = b5[0], a1e = b5[1], a2e = b5[2];
        #pragma unroll
        for (int c = 0; c < 16; ++c) {
            float xv = A->h3[c * 480 + pp];
            float x4 = fmaf(xv, w4[c * 4 + j], b4[c * 4 + j]);
            float h  = fmaxf((x4 - A->m4s[c]) * A->r4s[c], 0.f);
            a0e = fmaf(w5[c],      h, a0e);
            a1e = fmaf(w5[16 + c], h, a1e);
            a2e = fmaf(w5[32 + c], h, a2e);
        }
        float px = tanhf(a0e) * 64.f + 63.5f;
        float py = tanhf(a1e) * 64.f + 63.5f;
        float pz = tanhf(a2e) * 64.f + 63.5f;
        float val = 1.f / (1.f + expf(-qval[p]));

        float4 pv; pv.x = px; pv.y = py; pv.z = pz; pv.w = val;
        pts[b * NPT + p] = pv;

        int x0 = (int)floorf(px), y0 = (int)floorf(py), z0 = (int)floorf(pz);
        int xlo = max(0, x0 - 3), xhi = min(127, x0 + 4);
        int ylo = max(0, y0 - 3), yhi = min(127, y0 + 4);
        int zlo = max(0, z0 - 3), zhi = min(127, z0 + 4);
        if (xlo > xhi || ylo > yhi || zlo > zhi) continue;
        int pxl = xlo >> 4, pxh = xhi >> 4;   // x-pair index
        int tyl = ylo >> 3, tyh = yhi >> 3;
        int tzl = zlo >> 3, tzh = zhi >> 3;
        for (int tz = tzl; tz <= tzh; ++tz)
            for (int ty = tyl; ty <= tyh; ++ty)
                for (int px2 = pxl; px2 <= pxh; ++px2)
                    A->lflags[(tz * 16 + ty) * 8 + px2] = 1;
    }
    __syncthreads();

    // compact this batch's active pairs into its list segment
    for (int u = t; u < 2048; u += 256) {
        if (A->lflags[u]) {
            int pos = atomicAdd(&A->lcount, 1);
            list[b * 2048 + pos] = (b << 11) | u;
        }
    }
    __syncthreads();
    if (t == 0) bcount[b] = A->lcount;
}

// ---------------------------------------------------------------------------
// Tile phase (device fn): grid-stride over concatenated per-batch active
// lists. 256 threads, one 34.5 KB tile. Splat -> in-place register-rolling
// z/y/x smooth -> divide -> store 16x8x8. In-place safety: output index g
// only overwrites input g, which no later output of the column reads;
// columns are thread-private.
// ---------------------------------------------------------------------------
__device__ void tiles_phase(SMem* S, int t, int bid, int grid,
    const float4* __restrict__ pts, const int* __restrict__ bcount,
    const int* __restrict__ list, float* __restrict__ out)
{
    SMemB* Bm = &S->b;
    if (t < 16) Bm->bc[t] = bcount[t];
    __syncthreads();
    int total = 0;
    #pragma unroll
    for (int i = 0; i < 16; ++i) total += Bm->bc[i];

    float2* raw = Bm->raw;

    for (int idx = bid; idx < total; idx += grid) {
        int rem = idx, bb = 0;
        #pragma unroll 1
        for (; bb < 15; ++bb) { int c = Bm->bc[bb]; if (rem < c) break; rem -= c; }
        const int code = list[bb * 2048 + rem];
        const int pair = code & 7;
        const int ty   = (code >> 3) & 15;
        const int tz   = (code >> 7) & 15;
        const int pb_  = code >> 11;
        const int Tx = pair * 16, Ty = ty * 8, Tz = tz * 8;
        float* ob = out + (((size_t)(pb_ * NVOX + Tz) * NVOX + Ty) * NVOX + Tx);

        {   // zero the LDS tile (float4 fill)
            float4* rz = (float4*)raw;
            for (int u = t; u < 2156; u += 256) rz[u] = make_float4(0.f, 0.f, 0.f, 0.f);
        }
        __syncthreads();

        // scatter this batch's points (raw covers [T-3, T+{19,11,11}))
        const float4* pbp = pts + pb_ * NPT;
        for (int p = t; p < NPT; p += 256) {
            float4 pt = pbp[p];
            float x0f = floorf(pt.x), y0f = floorf(pt.y), z0f = floorf(pt.z);
            int x0 = (int)x0f, y0 = (int)y0f, z0 = (int)z0f;
            int lx0 = x0 - Tx + 3, ly0 = y0 - Ty + 3, lz0 = z0 - Tz + 3;
            if (lx0 + 1 < 0 || lx0 > 21 || ly0 + 1 < 0 || ly0 > 13 ||
                lz0 + 1 < 0 || lz0 > 13) continue;
            float fx = pt.x - x0f, fy = pt.y - y0f, fz = pt.z - z0f;
            float val = pt.w;
            #pragma unroll
            for (int dz = 0; dz < 2; ++dz) {
                int zi = z0 + dz, lz = lz0 + dz;
                if ((unsigned)zi >= 128u || (unsigned)lz >= 14u) continue;
                float wz = dz ? fz : 1.f - fz;
                #pragma unroll
                for (int dy = 0; dy < 2; ++dy) {
                    int yi = y0 + dy, ly = ly0 + dy;
                    if ((unsigned)yi >= 128u || (unsigned)ly >= 14u) continue;
                    float wy = dy ? fy : 1.f - fy;
                    #pragma unroll
                    for (int dx = 0; dx < 2; ++dx) {
                        int xi = x0 + dx, lx = lx0 + dx;
                        if ((unsigned)xi >= 128u || (unsigned)lx >= 22u) continue;
                        float w = (dx ? fx : 1.f - fx) * wy * wz;
                        float2* cell = &raw[(lz * 14 + ly) * 22 + lx];
                        atomicAdd(&cell->x, w * val);
                        atomicAdd(&cell->y, w);
                    }
                }
            }
        }
        __syncthreads();

        // z-pass IN PLACE: columns (ly,lx), stride 308; 14 reads -> 8 outputs
        for (int c = t; c < 308; c += 256) {
            float2 w0 = raw[c],            w1_ = raw[c + 308],
                   w2_ = raw[c + 2 * 308], w3_ = raw[c + 3 * 308],
                   w4_ = raw[c + 4 * 308], w5_ = raw[c + 5 * 308],
                   w6_ = raw[c + 6 * 308];
            #pragma unroll
            for (int z = 0; z < 8; ++z) {
                float cm1, c0, cp1; coef(Tz + z, cm1, c0, cp1);
                float sx = (w0.x + w6_.x) + 3.f * (w1_.x + w5_.x)
                         + cm1 * w2_.x + c0 * w3_.x + cp1 * w4_.x;
                float sy = (w0.y + w6_.y) + 3.f * (w1_.y + w5_.y)
                         + cm1 * w2_.y + c0 * w3_.y + cp1 * w4_.y;
                float2 nxt = raw[c + ((z < 7) ? z + 7 : 7) * 308];
                raw[c + z * 308] = f2(sx * (1.f / 27.f), sy * (1.f / 27.f));
                w0 = w1_; w1_ = w2_; w2_ = w3_; w3_ = w4_; w4_ = w5_; w5_ = w6_; w6_ = nxt;
            }
        }
        __syncthreads();

        // y-pass IN PLACE: columns (z,lx), z<8, stride 22
        if (t < 176) {
            int z = t / 22, lx = t - z * 22;
            float2* base = &raw[z * 308 + lx];
            float2 w0 = base[0],       w1_ = base[22],
                   w2_ = base[2 * 22], w3_ = base[3 * 22],
                   w4_ = base[4 * 22], w5_ = base[5 * 22],
                   w6_ = base[6 * 22];
            #pragma unroll
            for (int y = 0; y < 8; ++y) {
                float cm1, c0, cp1; coef(Ty + y, cm1, c0, cp1);
                float sx = (w0.x + w6_.x) + 3.f * (w1_.x + w5_.x)
                         + cm1 * w2_.x + c0 * w3_.x + cp1 * w4_.x;
                float sy = (w0.y + w6_.y) + 3.f * (w1_.y + w5_.y)
                         + cm1 * w2_.y + c0 * w3_.y + cp1 * w4_.y;
                float2 nxt = base[((y < 7) ? y + 7 : 7) * 22];
                base[y * 22] = f2(sx * (1.f / 27.f), sy * (1.f / 27.f));
                w0 = w1_; w1_ = w2_; w2_ = w3_; w3_ = w4_; w4_ = w5_; w5_ = w6_; w6_ = nxt;
            }
        }
        __syncthreads();

        // x-pass + division: 2 threads per (z,y) row, 8 outputs each
        if (t < 128) {
            int row = t >> 1, hx = t & 1;
            int z = row >> 3, y = row & 7;
            const float2* a = &raw[z * 308 + y * 22 + hx * 8];
            float2 w0 = a[0], w1_ = a[1], w2_ = a[2], w3_ = a[3],
                   w4_ = a[4], w5_ = a[5], w6_ = a[6];
            float res[8];
            #pragma unroll
            for (int i = 0; i < 8; ++i) {
                int x = hx * 8 + i;
                float cm1, c0, cp1; coef(Tx + x, cm1, c0, cp1);
                float sx = (w0.x + w6_.x) + 3.f * (w1_.x + w5_.x)
                         + cm1 * w2_.x + c0 * w3_.x + cp1 * w4_.x;
                float sy = (w0.y + w6_.y) + 3.f * (w1_.y + w5_.y)
                         + cm1 * w2_.y + c0 * w3_.y + cp1 * w4_.y;
                res[i] = (sx * (1.f / 27.f)) / (sy * (1.f / 27.f) + 0.001f);
                float2 nxt = a[(i < 7) ? i + 7 : 13];
                w0 = w1_; w1_ = w2_; w2_ = w3_; w3_ = w4_; w4_ = w5_; w5_ = w6_; w6_ = nxt;
            }
            float* orow = &ob[((size_t)z * NVOX + y) * NVOX + hx * 8];
            *(float4*)&orow[0] = make_float4(res[0], res[1], res[2], res[3]);
            *(float4*)&orow[4] = make_float4(res[4], res[5], res[6], res[7]);
        }
        __syncthreads();   // raw re-zeroed next iteration
    }
}

#define TAIL_ARGS const float* __restrict__ q, const float* __restrict__ w1,  \
    const float* __restrict__ b1, const float* __restrict__ qval,             \
    const float* __restrict__ w2, const float* __restrict__ b2,               \
    const float* __restrict__ w3, const float* __restrict__ b3,               \
    const float* __restrict__ w4, const float* __restrict__ b4,               \
    const float* __restrict__ w5, const float* __restrict__ b5,               \
    float4* __restrict__ pts, int* __restrict__ bcount,                       \
    int* __restrict__ list

// ---------------------------------------------------------------------------
// Cooperative fused kernel: blocks 0-15 run the tail; grid.sync; all blocks
// grid-stride the active tiles. Every output byte in this kernel has exactly
// ONE writer (zeros were flushed by the preceding zero_out kernel boundary).
// ---------------------------------------------------------------------------
__global__ __launch_bounds__(256, 4)
void mega(TAIL_ARGS, float* __restrict__ out)
{
    __shared__ SMem sm;
    const int bid = blockIdx.x;
    const int t = threadIdx.x;

    if (bid < NB)
        tail_phase(&sm, bid, t, q, w1, b1, qval, w2, b2, w3, b3,
                   w4, b4, w5, b5, pts, bcount, list);

    __threadfence();            // release pts/list/bcount (device scope)
    cg::this_grid().sync();
    __threadfence();            // acquire side

    tiles_phase(&sm, t, bid, gridDim.x, pts, bcount, list, out);
}

// Fallback kernels (same device code, ordinary launches).
__global__ __launch_bounds__(256, 4)
void tail_k(TAIL_ARGS)
{
    __shared__ SMem sm;
    tail_phase(&sm, blockIdx.x, threadIdx.x, q, w1, b1, qval, w2, b2,
               w3, b3, w4, b4, w5, b5, pts, bcount, list);
}

__global__ __launch_bounds__(256, 4)
void tile_k(const float4* __restrict__ pts, const int* __restrict__ bcount,
            const int* __restrict__ list, float* __restrict__ out)
{
    __shared__ SMem sm;
    tiles_phase(&sm, threadIdx.x, blockIdx.x, gridDim.x, pts, bcount, list, out);
}

// ---------------------------------------------------------------------------
extern "C" void kernel_launch(void* const* d_in, const int* in_sizes, int n_in,
                              void* d_out, int out_size, void* d_ws, size_t ws_size,
                              hipStream_t stream)
{
    const float* q    = (const float*)d_in[0];
    const float* qval = (const float*)d_in[1];
    const float* w1   = (const float*)d_in[2];
    const float* b1   = (const float*)d_in[3];
    const float* w2   = (const float*)d_in[4];
    const float* b2   = (const float*)d_in[5];
    const float* w3   = (const float*)d_in[6];
    const float* b3   = (const float*)d_in[7];
    const float* w4   = (const float*)d_in[8];
    const float* b4   = (const float*)d_in[9];
    const float* w5   = (const float*)d_in[10];
    const float* b5   = (const float*)d_in[11];
    float* out = (float*)d_out;

    // ws layout:
    //   [0,       64)   bcount (16 ints, padded)
    //   [64,  131136)   list (16 batches x 2048 ints)
    //   [131136, 622656) pts (1920*16 float4)
    int*    bcount = (int*)d_ws;
    int*    list   = (int*)((char*)d_ws + 64);
    float4* pts    = (float4*)((char*)d_ws + 131136);

    zero_out<<<4096, 256, 0, stream>>>((float4*)out);

    bool coop_ok = false;
    int occ = 0;
    if (hipOccupancyMaxActiveBlocksPerMultiprocessor(
            &occ, (const void*)mega, 256, 0) == hipSuccess && occ > 0) {
        int nblk = occ * 256;
        if (nblk > 1024) nblk = 1024;
        if (nblk >= NB) {
            void* args[] = { &q, &w1, &b1, &qval, &w2, &b2, &w3, &b3,
                             &w4, &b4, &w5, &b5, &pts, &bcount, &list, &out };
            coop_ok = (hipLaunchCooperativeKernel((const void*)mega,
                           dim3(nblk), dim3(256), args, 0, stream)
                       == hipSuccess);
        }
    }

    if (!coop_ok) {
        // Verified round-4-style fallback (no memset needed: bcount/list/pts
        // are fully rewritten every launch).
        tail_k<<<NB, 256, 0, stream>>>(q, w1, b1, qval, w2, b2, w3, b3,
                                       w4, b4, w5, b5, pts, bcount, list);
        tile_k<<<1024, 256, 0, stream>>>(pts, bcount, list, out);
    }
}

// Round 7
// 242.720 us; speedup vs baseline: 2.0282x; 2.0282x over previous
//
#include <hip/hip_runtime.h>
#include <cstddef>

// Problem constants
#define NB 16
#define NVOX 128
#define NPT 1920

static __device__ __forceinline__ float2 f2(float a, float b) {
    float2 r; r.x = a; r.y = b; return r;
}

// Per-axis composed 7-tap coefficients (A^3 of zero-padded 3-tap average):
// interior [1,3,6,7,6,3,1]/27; boundary rows via cm1/c0/cp1 overrides.
__device__ __forceinline__ void coef(int g, float& cm1, float& c0, float& cp1)
{
    cm1 = (g == 1 || g == 127) ? 5.f : 6.f;
    c0  = (g == 0 || g == 127) ? 4.f : 7.f;
    cp1 = (g == 0 || g == 126) ? 5.f : 6.f;
}

// ---------------------------------------------------------------------------
// Zero the whole output at full write BW (proven ~21 us @ ~80% write BW).
// ---------------------------------------------------------------------------
__global__ __launch_bounds__(256)
void zero_out(float4* __restrict__ out)
{
    int idx = blockIdx.x * 2048 + threadIdx.x;
    #pragma unroll
    for (int i = 0; i < 8; ++i)
        out[idx + i * 256] = make_float4(0.f, 0.f, 0.f, 0.f);
}

// ---------------------------------------------------------------------------
// Tail: stage1 GEMM + wave-per-channel MLP + point gen + per-batch LDS
// compaction. One block per batch, 1024 threads (R4-verified logic; R6-
// verified per-batch bcount/list compaction).
// ---------------------------------------------------------------------------
__global__ __launch_bounds__(1024)
void tail_k(const float* __restrict__ q, const float* __restrict__ w1,
            const float* __restrict__ b1, const float* __restrict__ qval,
            const float* __restrict__ w2, const float* __restrict__ b2,
            const float* __restrict__ w3, const float* __restrict__ b3,
            const float* __restrict__ w4, const float* __restrict__ b4,
            const float* __restrict__ w5, const float* __restrict__ b5,
            float4* __restrict__ pts, int* __restrict__ bcount,
            int* __restrict__ list)
{
    __shared__ float x1s[1920];          // stage1 output, flat (64,30)
    __shared__ float h3[7680];           // relu'd IN3; first 2048 double as qs
    __shared__ float m4s[16], r4s[16];
    __shared__ unsigned char lflags[2048];   // tz16 * ty16 * px8 pair flags
    __shared__ int lcount;

    const int b = blockIdx.x;
    const int t = threadIdx.x;
    float* qs = h3;    // overlay: h3 not live until after stage1

    for (int u = t; u < 2048; u += 1024) {
        qs[u] = q[b * 2048 + u];
        lflags[u] = 0;
    }
    if (t == 0) lcount = 0;
    __syncthreads();

    // stage1: x1[(o,l)] = b1[o] + sum_i w1[o,i] * q[b, i*8+l]
    for (int u = t; u < 1920; u += 1024) {
        int o = u >> 3, l = u & 7;
        const float4* wr = (const float4*)(w1 + o * 256);
        float acc = 0.f;
        #pragma unroll 8
        for (int i4 = 0; i4 < 64; ++i4) {
            float4 w = wr[i4];
            int base = i4 * 32 + l;
            acc = fmaf(w.x, qs[base],      acc);
            acc = fmaf(w.y, qs[base + 8],  acc);
            acc = fmaf(w.z, qs[base + 16], acc);
            acc = fmaf(w.w, qs[base + 24], acc);
        }
        x1s[u] = b1[o] + acc;
    }
    __syncthreads();   // qs dead from here; h3 live

    // wave-per-channel chain: wave w == final channel c3
    const int l = t & 63;
    const int c1l = l >> 4;
    const int p16 = l & 15;
    const bool hasb = (p16 < 14);    // second element p16+16 < 30
    {
        const int c3 = t >> 6;
        const int c1 = 4 * c3 + c1l;
        const float* xrow = x1s + c1 * 30;
        float a0 = xrow[p16];
        float a1 = hasb ? xrow[p16 + 16] : 0.f;

        // IN1 over 30 elems: butterfly within 16-lane channel group
        float s = a0 + a1, s2 = a0 * a0 + a1 * a1;
        #pragma unroll
        for (int m = 1; m <= 8; m <<= 1) {
            s  += __shfl_xor(s,  m);
            s2 += __shfl_xor(s2, m);
        }
        float mean = s * (1.f / 30.f);
        float var  = s2 * (1.f / 30.f) - mean * mean;
        float rstd = rsqrtf(var + 1e-5f);
        a0 = fmaxf((a0 - mean) * rstd, 0.f);
        a1 = fmaxf((a1 - mean) * rstd, 0.f);   // garbage if !hasb; masked

        // stage2: grouped conv 64->128
        const float w20 = w2[c1 * 2 + 0], w21 = w2[c1 * 2 + 1];
        const float b20 = b2[c1 * 2 + 0], b21 = b2[c1 * 2 + 1];
        float y00 = fmaf(a0, w20, b20), y01 = fmaf(a0, w21, b21);
        float y10 = fmaf(a1, w20, b20), y11 = fmaf(a1, w21, b21);

        // IN2 over 120 elems: butterfly within 32-lane half
        float u1 = y00 + y01 + (hasb ? (y10 + y11) : 0.f);
        float u2 = y00 * y00 + y01 * y01
                 + (hasb ? (y10 * y10 + y11 * y11) : 0.f);
        #pragma unroll
        for (int m = 1; m <= 16; m <<= 1) {
            u1 += __shfl_xor(u1, m);
            u2 += __shfl_xor(u2, m);
        }
        mean = u1 * (1.f / 120.f);
        var  = u2 * (1.f / 120.f) - mean * mean;
        rstd = rsqrtf(var + 1e-5f);
        y00 = fmaxf((y00 - mean) * rstd, 0.f);
        y01 = fmaxf((y01 - mean) * rstd, 0.f);
        y10 = fmaxf((y10 - mean) * rstd, 0.f);
        y11 = fmaxf((y11 - mean) * rstd, 0.f);

        // stage3: grouped conv 32->64
        const int c2 = c1 >> 1;
        const float w30 = w3[c2 * 2 + 0], w31 = w3[c2 * 2 + 1];
        const float b30 = b3[c2 * 2 + 0], b31 = b3[c2 * 2 + 1];
        float z000 = fmaf(y00, w30, b30), z001 = fmaf(y00, w31, b31);
        float z010 = fmaf(y01, w30, b30), z011 = fmaf(y01, w31, b31);
        float z100 = fmaf(y10, w30, b30), z101 = fmaf(y10, w31, b31);
        float z110 = fmaf(y11, w30, b30), z111 = fmaf(y11, w31, b31);

        // IN3 over 480 elems: full-wave butterfly
        float v1 = z000 + z001 + z010 + z011
                 + (hasb ? (z100 + z101 + z110 + z111) : 0.f);
        float v2 = z000 * z000 + z001 * z001 + z010 * z010 + z011 * z011
                 + (hasb ? (z100 * z100 + z101 * z101
                          + z110 * z110 + z111 * z111) : 0.f);
        #pragma unroll
        for (int m = 1; m <= 32; m <<= 1) {
            v1 += __shfl_xor(v1, m);
            v2 += __shfl_xor(v2, m);
        }
        mean = v1 * (1.f / 480.f);
        var  = v2 * (1.f / 480.f) - mean * mean;
        rstd = rsqrtf(var + 1e-5f);

        // normalize+relu -> h3; accumulate relu'd sums for IN4 stats
        // p(global in 480) = ((c2&1)*2 + j2)*120 + ((c1&1)*2 + j1)*30 + p1
        const int qb0 = (c1l >> 1) * 240;
        const int pb0 = (c1l & 1) * 60;
        float* hw = h3 + c3 * 480;
        float s4 = 0.f, q4 = 0.f;
        {
            float v;
            v = fmaxf((z000 - mean) * rstd, 0.f); hw[qb0 +       pb0 +      p16] = v; s4 += v; q4 += v * v;
            v = fmaxf((z001 - mean) * rstd, 0.f); hw[qb0 + 120 + pb0 +      p16] = v; s4 += v; q4 += v * v;
            v = fmaxf((z010 - mean) * rstd, 0.f); hw[qb0 +       pb0 + 30 + p16] = v; s4 += v; q4 += v * v;
            v = fmaxf((z011 - mean) * rstd, 0.f); hw[qb0 + 120 + pb0 + 30 + p16] = v; s4 += v; q4 += v * v;
            if (hasb) {
                v = fmaxf((z100 - mean) * rstd, 0.f); hw[qb0 +       pb0 +      p16 + 16] = v; s4 += v; q4 += v * v;
                v = fmaxf((z101 - mean) * rstd, 0.f); hw[qb0 + 120 + pb0 +      p16 + 16] = v; s4 += v; q4 += v * v;
                v = fmaxf((z110 - mean) * rstd, 0.f); hw[qb0 +       pb0 + 30 + p16 + 16] = v; s4 += v; q4 += v * v;
                v = fmaxf((z111 - mean) * rstd, 0.f); hw[qb0 + 120 + pb0 + 30 + p16 + 16] = v; s4 += v; q4 += v * v;
            }
        }
        #pragma unroll
        for (int m = 1; m <= 32; m <<= 1) {
            s4 += __shfl_xor(s4, m);
            q4 += __shfl_xor(q4, m);
        }
        if (l == 0) {
            // stage4 IN stats analytically:
            // x4[c, j*480+p] = h3[c,p]*w4[c*4+j] + b4[c*4+j]
            float sum4 = 0.f, sq4 = 0.f;
            #pragma unroll
            for (int j = 0; j < 4; ++j) {
                float ww = w4[c3 * 4 + j], bb = b4[c3 * 4 + j];
                sum4 += ww * s4 + 480.f * bb;
                sq4  += ww * ww * q4 + 2.f * ww * bb * s4 + 480.f * bb * bb;
            }
            float m4 = sum4 * (1.f / 1920.f);
            float var4 = sq4 * (1.f / 1920.f) - m4 * m4;
            m4s[c3] = m4; r4s[c3] = rsqrtf(var4 + 1e-5f);
        }
    }
    __syncthreads();

    // per-point: stage4 apply + stage5 einsum + tanh + emit + mark pairs
    for (int p = t; p < NPT; p += 1024) {
        int j = p / 480;
        int pp = p - j * 480;
        float a0e = b5[0], a1e = b5[1], a2e = b5[2];
        #pragma unroll
        for (int c = 0; c < 16; ++c) {
            float xv = h3[c * 480 + pp];
            float x4 = fmaf(xv, w4[c * 4 + j], b4[c * 4 + j]);
            float h  = fmaxf((x4 - m4s[c]) * r4s[c], 0.f);
            a0e = fmaf(w5[c],      h, a0e);
            a1e = fmaf(w5[16 + c], h, a1e);
            a2e = fmaf(w5[32 + c], h, a2e);
        }
        float px = tanhf(a0e) * 64.f + 63.5f;
        float py = tanhf(a1e) * 64.f + 63.5f;
        float pz = tanhf(a2e) * 64.f + 63.5f;
        float val = 1.f / (1.f + expf(-qval[p]));

        float4 pv; pv.x = px; pv.y = py; pv.z = pz; pv.w = val;
        pts[b * NPT + p] = pv;

        int x0 = (int)floorf(px), y0 = (int)floorf(py), z0 = (int)floorf(pz);
        int xlo = max(0, x0 - 3), xhi = min(127, x0 + 4);
        int ylo = max(0, y0 - 3), yhi = min(127, y0 + 4);
        int zlo = max(0, z0 - 3), zhi = min(127, z0 + 4);
        if (xlo > xhi || ylo > yhi || zlo > zhi) continue;
        int pxl = xlo >> 4, pxh = xhi >> 4;   // x-pair index
        int tyl = ylo >> 3, tyh = yhi >> 3;
        int tzl = zlo >> 3, tzh = zhi >> 3;
        for (int tz = tzl; tz <= tzh; ++tz)
            for (int ty = tyl; ty <= tyh; ++ty)
                for (int px2 = pxl; px2 <= pxh; ++px2)
                    lflags[(tz * 16 + ty) * 8 + px2] = 1;
    }
    __syncthreads();

    // compact this batch's active pairs into its list segment
    for (int u = t; u < 2048; u += 1024) {
        if (lflags[u]) {
            int pos = atomicAdd(&lcount, 1);
            list[b * 2048 + pos] = (b << 11) | u;
        }
    }
    __syncthreads();
    if (t == 0) bcount[b] = lcount;
}

// ---------------------------------------------------------------------------
// Tile helpers (bodies verbatim from the round-2/6 verified kernels).
// ---------------------------------------------------------------------------
__device__ __forceinline__ void decode_tile(const int* pf, const int* __restrict__ list,
                                            int idx, int& Tx, int& Ty, int& Tz, int& pb_)
{
    int bb = 0;
    #pragma unroll 1
    for (; bb < 15; ++bb) if (idx < pf[bb + 1]) break;
    int code = list[bb * 2048 + (idx - pf[bb])];
    pb_ = code >> 11;
    Tx = (code & 7) * 16;
    Ty = ((code >> 3) & 15) * 8;
    Tz = ((code >> 7) & 15) * 8;
}

__device__ __forceinline__ void zero_buf(float2* raw, int th, int stride)
{
    float4* rz = (float4*)raw;
    for (int u = th; u < 2156; u += stride)
        rz[u] = make_float4(0.f, 0.f, 0.f, 0.f);
}

__device__ __forceinline__ void scatter(float2* raw, const float4* __restrict__ pbp,
                                        int lo, int hi, int th, int stride,
                                        int Tx, int Ty, int Tz)
{
    for (int p = lo + th; p < hi; p += stride) {
        float4 pt = pbp[p];
        float x0f = floorf(pt.x), y0f = floorf(pt.y), z0f = floorf(pt.z);
        int x0 = (int)x0f, y0 = (int)y0f, z0 = (int)z0f;
        int lx0 = x0 - Tx + 3, ly0 = y0 - Ty + 3, lz0 = z0 - Tz + 3;
        if (lx0 + 1 < 0 || lx0 > 21 || ly0 + 1 < 0 || ly0 > 13 ||
            lz0 + 1 < 0 || lz0 > 13) continue;
        float fx = pt.x - x0f, fy = pt.y - y0f, fz = pt.z - z0f;
        float val = pt.w;
        #pragma unroll
        for (int dz = 0; dz < 2; ++dz) {
            int zi = z0 + dz, lz = lz0 + dz;
            if ((unsigned)zi >= 128u || (unsigned)lz >= 14u) continue;
            float wz = dz ? fz : 1.f - fz;
            #pragma unroll
            for (int dy = 0; dy < 2; ++dy) {
                int yi = y0 + dy, ly = ly0 + dy;
                if ((unsigned)yi >= 128u || (unsigned)ly >= 14u) continue;
                float wy = dy ? fy : 1.f - fy;
                #pragma unroll
                for (int dx = 0; dx < 2; ++dx) {
                    int xi = x0 + dx, lx = lx0 + dx;
                    if ((unsigned)xi >= 128u || (unsigned)lx >= 22u) continue;
                    float w = (dx ? fx : 1.f - fx) * wy * wz;
                    float2* cell = &raw[(lz * 14 + ly) * 22 + lx];
                    atomicAdd(&cell->x, w * val);
                    atomicAdd(&cell->y, w);
                }
            }
        }
    }
}

__device__ __forceinline__ void zpass(float2* raw, int Tz, int th)
{
    for (int c = th; c < 308; c += 256) {
        float2 w0 = raw[c],            w1_ = raw[c + 308],
               w2_ = raw[c + 2 * 308], w3_ = raw[c + 3 * 308],
               w4_ = raw[c + 4 * 308], w5_ = raw[c + 5 * 308],
               w6_ = raw[c + 6 * 308];
        #pragma unroll
        for (int z = 0; z < 8; ++z) {
            float cm1, c0, cp1; coef(Tz + z, cm1, c0, cp1);
            float sx = (w0.x + w6_.x) + 3.f * (w1_.x + w5_.x)
                     + cm1 * w2_.x + c0 * w3_.x + cp1 * w4_.x;
            float sy = (w0.y + w6_.y) + 3.f * (w1_.y + w5_.y)
                     + cm1 * w2_.y + c0 * w3_.y + cp1 * w4_.y;
            float2 nxt = raw[c + ((z < 7) ? z + 7 : 7) * 308];
            raw[c + z * 308] = f2(sx * (1.f / 27.f), sy * (1.f / 27.f));
            w0 = w1_; w1_ = w2_; w2_ = w3_; w3_ = w4_; w4_ = w5_; w5_ = w6_; w6_ = nxt;
        }
    }
}

__device__ __forceinline__ void ypass(float2* raw, int Ty, int th)
{
    if (th < 176) {
        int z = th / 22, lx = th - z * 22;
        float2* base = &raw[z * 308 + lx];
        float2 w0 = base[0],       w1_ = base[22],
               w2_ = base[2 * 22], w3_ = base[3 * 22],
               w4_ = base[4 * 22], w5_ = base[5 * 22],
               w6_ = base[6 * 22];
        #pragma unroll
        for (int y = 0; y < 8; ++y) {
            float cm1, c0, cp1; coef(Ty + y, cm1, c0, cp1);
            float sx = (w0.x + w6_.x) + 3.f * (w1_.x + w5_.x)
                     + cm1 * w2_.x + c0 * w3_.x + cp1 * w4_.x;
            float sy = (w0.y + w6_.y) + 3.f * (w1_.y + w5_.y)
                     + cm1 * w2_.y + c0 * w3_.y + cp1 * w4_.y;
            float2 nxt = base[((y < 7) ? y + 7 : 7) * 22];
            base[y * 22] = f2(sx * (1.f / 27.f), sy * (1.f / 27.f));
            w0 = w1_; w1_ = w2_; w2_ = w3_; w3_ = w4_; w4_ = w5_; w5_ = w6_; w6_ = nxt;
        }
    }
}

__device__ __forceinline__ void xpass(float2* raw, int Tx, float* __restrict__ ob, int th)
{
    if (th < 128) {
        int row = th >> 1, hx = th & 1;
        int z = row >> 3, y = row & 7;
        const float2* a = &raw[z * 308 + y * 22 + hx * 8];
        float2 w0 = a[0], w1_ = a[1], w2_ = a[2], w3_ = a[3],
               w4_ = a[4], w5_ = a[5], w6_ = a[6];
        float res[8];
        #pragma unroll
        for (int i = 0; i < 8; ++i) {
            int x = hx * 8 + i;
            float cm1, c0, cp1; coef(Tx + x, cm1, c0, cp1);
            float sx = (w0.x + w6_.x) + 3.f * (w1_.x + w5_.x)
                     + cm1 * w2_.x + c0 * w3_.x + cp1 * w4_.x;
            float sy = (w0.y + w6_.y) + 3.f * (w1_.y + w5_.y)
                     + cm1 * w2_.y + c0 * w3_.y + cp1 * w4_.y;
            res[i] = (sx * (1.f / 27.f)) / (sy * (1.f / 27.f) + 0.001f);
            float2 nxt = a[(i < 7) ? i + 7 : 13];
            w0 = w1_; w1_ = w2_; w2_ = w3_; w3_ = w4_; w4_ = w5_; w5_ = w6_; w6_ = nxt;
        }
        float* orow = &ob[((size_t)z * NVOX + y) * NVOX + hx * 8];
        *(float4*)&orow[0] = make_float4(res[0], res[1], res[2], res[3]);
        *(float4*)&orow[4] = make_float4(res[4], res[5], res[6], res[7]);
    }
}

// ---------------------------------------------------------------------------
// Pipelined tile kernel: 512 blocks x 512 threads, 2 blocks/CU (69 KB LDS).
// Blocked index ranges (consecutive tiles share a batch -> pts stay in L1).
// Per iteration: waves 0-3 smooth tile k (z / y / x+store) while waves 4-7
// prep tile k+1 (zero LDS / scatter half / scatter half) in the other
// buffer. 3 barriers per tile instead of 6; scatter L2 latency hides under
// smoothing VALU/LDS work.
// ---------------------------------------------------------------------------
__global__ __launch_bounds__(512, 4)
void tile_k(const float4* __restrict__ pts, const int* __restrict__ bcount,
            const int* __restrict__ list, float* __restrict__ out)
{
    __shared__ float2 bufA[4312];
    __shared__ float2 bufB[4312];
    __shared__ int pf[17];

    const int t = threadIdx.x;
    if (t < 16) pf[t + 1] = bcount[t];
    if (t == 0) pf[0] = 0;
    __syncthreads();
    if (t == 0) {
        int s = 0;
        #pragma unroll
        for (int i = 1; i <= 16; ++i) { s += pf[i]; pf[i] = s; }
    }
    __syncthreads();

    const int total = pf[16];
    const int grid = gridDim.x;
    const int chunk = (total + grid - 1) / grid;
    int idx = blockIdx.x * chunk;
    const int end = min(idx + chunk, total);
    if (idx >= end) return;

    int cTx, cTy, cTz, cPb;
    decode_tile(pf, list, idx, cTx, cTy, cTz, cPb);
    float2* cur = bufA;
    float2* nxt = bufB;

    // prologue: zero + scatter tile idx into cur with all 512 threads
    zero_buf(cur, t, 512);
    __syncthreads();
    scatter(cur, pts + cPb * NPT, 0, NPT, t, 512, cTx, cTy, cTz);
    __syncthreads();

    const int w8 = t >> 6;
    const bool low = (w8 < 4);
    const int th = t & 255;

    while (true) {
        const bool have_next = (idx + 1) < end;
        int nTx = 0, nTy = 0, nTz = 0, nPb = 0;
        if (have_next)
            decode_tile(pf, list, idx + 1, nTx, nTy, nTz, nPb);

        // Phase A: z-pass(cur) || zero(nxt)
        if (low) zpass(cur, cTz, th);
        else if (have_next) zero_buf(nxt, th, 256);
        __syncthreads();

        // Phase B: y-pass(cur) || scatter first half into nxt
        if (low) ypass(cur, cTy, th);
        else if (have_next)
            scatter(nxt, pts + nPb * NPT, 0, 960, th, 256, nTx, nTy, nTz);
        __syncthreads();

        // Phase C: x-pass+store(cur) || scatter second half into nxt
        if (low) {
            float* ob = out + (((size_t)(cPb * NVOX + cTz) * NVOX + cTy) * NVOX + cTx);
            xpass(cur, cTx, ob, th);
        } else if (have_next)
            scatter(nxt, pts + nPb * NPT, 960, NPT, th, 256, nTx, nTy, nTz);
        __syncthreads();

        if (!have_next) break;
        ++idx;
        float2* tmp = cur; cur = nxt; nxt = tmp;
        cTx = nTx; cTy = nTy; cTz = nTz; cPb = nPb;
    }
}

// ---------------------------------------------------------------------------
extern "C" void kernel_launch(void* const* d_in, const int* in_sizes, int n_in,
                              void* d_out, int out_size, void* d_ws, size_t ws_size,
                              hipStream_t stream)
{
    const float* q    = (const float*)d_in[0];
    const float* qval = (const float*)d_in[1];
    const float* w1   = (const float*)d_in[2];
    const float* b1   = (const float*)d_in[3];
    const float* w2   = (const float*)d_in[4];
    const float* b2   = (const float*)d_in[5];
    const float* w3   = (const float*)d_in[6];
    const float* b3   = (const float*)d_in[7];
    const float* w4   = (const float*)d_in[8];
    const float* b4   = (const float*)d_in[9];
    const float* w5   = (const float*)d_in[10];
    const float* b5   = (const float*)d_in[11];
    float* out = (float*)d_out;

    // ws layout:
    //   [0,       64)    bcount (16 ints, padded)
    //   [64,  131136)    list (16 batches x 2048 ints)
    //   [131136, 622656) pts (1920*16 float4)
    int*    bcount = (int*)d_ws;
    int*    list   = (int*)((char*)d_ws + 64);
    float4* pts    = (float4*)((char*)d_ws + 131136);

    zero_out<<<4096, 256, 0, stream>>>((float4*)out);

    tail_k<<<NB, 1024, 0, stream>>>(q, w1, b1, qval, w2, b2, w3, b3,
                                    w4, b4, w5, b5, pts, bcount, list);

    tile_k<<<512, 512, 0, stream>>>(pts, bcount, list, out);
}

// Round 8
// 235.865 us; speedup vs baseline: 2.0872x; 1.0291x over previous
//
#include <hip/hip_runtime.h>
#include <cstddef>

// Problem constants
#define NB 16
#define NVOX 128
#define NPT 1920

static __device__ __forceinline__ float2 f2(float a, float b) {
    float2 r; r.x = a; r.y = b; return r;
}

// Per-axis composed 7-tap coefficients (A^3 of zero-padded 3-tap average):
// interior [1,3,6,7,6,3,1]/27; boundary rows via cm1/c0/cp1 overrides.
__device__ __forceinline__ void coef(int g, float& cm1, float& c0, float& cp1)
{
    cm1 = (g == 1 || g == 127) ? 5.f : 6.f;
    c0  = (g == 0 || g == 127) ? 4.f : 7.f;
    cp1 = (g == 0 || g == 126) ? 5.f : 6.f;
}

// ---------------------------------------------------------------------------
// Fused tail + zero kernel, grid 512 x 1024.
// Blocks 0-15: per-batch MLP tail (R4-verified wave-per-channel chain) +
//   point gen + per-pair CSR (count -> LDS prefix-sum -> fill) + active-pair
//   compaction.
// Blocks 16-511: zero the 134 MB output at full write BW, overlapped with
//   the tail blocks. Every output byte: zeroed here, actives overwritten by
//   tile_k (separate kernel -> no intra-kernel write-write hazard).
// ---------------------------------------------------------------------------
__global__ __launch_bounds__(1024)
void tail_zero_k(const float* __restrict__ q, const float* __restrict__ w1,
                 const float* __restrict__ b1, const float* __restrict__ qval,
                 const float* __restrict__ w2, const float* __restrict__ b2,
                 const float* __restrict__ w3, const float* __restrict__ b3,
                 const float* __restrict__ w4, const float* __restrict__ b4,
                 const float* __restrict__ w5, const float* __restrict__ b5,
                 float4* __restrict__ pts, int* __restrict__ bcount,
                 int* __restrict__ list, int* __restrict__ rp,
                 int* __restrict__ ent, float4* __restrict__ out4)
{
    const int bid = blockIdx.x;
    const int t = threadIdx.x;

    if (bid >= NB) {
        // ---------------- zero phase (496 blocks) ----------------
        const int stride = 496 * 1024;
        for (int i = (bid - NB) * 1024 + t; i < (NB * NVOX * NVOX * NVOX) / 4;
             i += stride)
            out4[i] = make_float4(0.f, 0.f, 0.f, 0.f);
        return;
    }

    // ---------------- tail phase (16 blocks) ----------------
    __shared__ float x1s[1920];          // stage1 output, flat (64,30)
    __shared__ float h3[7680];           // relu'd IN3; first 2048 double as qs
    __shared__ float m4s[16], r4s[16];
    __shared__ int cnt[2048];            // per-pair point counts
    __shared__ int off[2048];            // fill cursors
    __shared__ int gsum[64];
    __shared__ int lcount;

    const int b = bid;
    float* qs = h3;    // overlay: h3 not live until after stage1

    for (int u = t; u < 2048; u += 1024) {
        qs[u] = q[b * 2048 + u];
        cnt[u] = 0;
    }
    if (t == 0) lcount = 0;
    __syncthreads();

    // stage1: x1[(o,l)] = b1[o] + sum_i w1[o,i] * q[b, i*8+l]
    for (int u = t; u < 1920; u += 1024) {
        int o = u >> 3, l = u & 7;
        const float4* wr = (const float4*)(w1 + o * 256);
        float acc = 0.f;
        #pragma unroll 8
        for (int i4 = 0; i4 < 64; ++i4) {
            float4 w = wr[i4];
            int base = i4 * 32 + l;
            acc = fmaf(w.x, qs[base],      acc);
            acc = fmaf(w.y, qs[base + 8],  acc);
            acc = fmaf(w.z, qs[base + 16], acc);
            acc = fmaf(w.w, qs[base + 24], acc);
        }
        x1s[u] = b1[o] + acc;
    }
    __syncthreads();   // qs dead from here; h3 live

    // wave-per-channel chain: wave w == final channel c3
    const int l = t & 63;
    const int c1l = l >> 4;
    const int p16 = l & 15;
    const bool hasb = (p16 < 14);    // second element p16+16 < 30
    {
        const int c3 = t >> 6;
        const int c1 = 4 * c3 + c1l;
        const float* xrow = x1s + c1 * 30;
        float a0 = xrow[p16];
        float a1 = hasb ? xrow[p16 + 16] : 0.f;

        // IN1 over 30 elems: butterfly within 16-lane channel group
        float s = a0 + a1, s2 = a0 * a0 + a1 * a1;
        #pragma unroll
        for (int m = 1; m <= 8; m <<= 1) {
            s  += __shfl_xor(s,  m);
            s2 += __shfl_xor(s2, m);
        }
        float mean = s * (1.f / 30.f);
        float var  = s2 * (1.f / 30.f) - mean * mean;
        float rstd = rsqrtf(var + 1e-5f);
        a0 = fmaxf((a0 - mean) * rstd, 0.f);
        a1 = fmaxf((a1 - mean) * rstd, 0.f);   // garbage if !hasb; masked

        // stage2: grouped conv 64->128
        const float w20 = w2[c1 * 2 + 0], w21 = w2[c1 * 2 + 1];
        const float b20 = b2[c1 * 2 + 0], b21 = b2[c1 * 2 + 1];
        float y00 = fmaf(a0, w20, b20), y01 = fmaf(a0, w21, b21);
        float y10 = fmaf(a1, w20, b20), y11 = fmaf(a1, w21, b21);

        // IN2 over 120 elems: butterfly within 32-lane half
        float u1 = y00 + y01 + (hasb ? (y10 + y11) : 0.f);
        float u2 = y00 * y00 + y01 * y01
                 + (hasb ? (y10 * y10 + y11 * y11) : 0.f);
        #pragma unroll
        for (int m = 1; m <= 16; m <<= 1) {
            u1 += __shfl_xor(u1, m);
            u2 += __shfl_xor(u2, m);
        }
        mean = u1 * (1.f / 120.f);
        var  = u2 * (1.f / 120.f) - mean * mean;
        rstd = rsqrtf(var + 1e-5f);
        y00 = fmaxf((y00 - mean) * rstd, 0.f);
        y01 = fmaxf((y01 - mean) * rstd, 0.f);
        y10 = fmaxf((y10 - mean) * rstd, 0.f);
        y11 = fmaxf((y11 - mean) * rstd, 0.f);

        // stage3: grouped conv 32->64
        const int c2 = c1 >> 1;
        const float w30 = w3[c2 * 2 + 0], w31 = w3[c2 * 2 + 1];
        const float b30 = b3[c2 * 2 + 0], b31 = b3[c2 * 2 + 1];
        float z000 = fmaf(y00, w30, b30), z001 = fmaf(y00, w31, b31);
        float z010 = fmaf(y01, w30, b30), z011 = fmaf(y01, w31, b31);
        float z100 = fmaf(y10, w30, b30), z101 = fmaf(y10, w31, b31);
        float z110 = fmaf(y11, w30, b30), z111 = fmaf(y11, w31, b31);

        // IN3 over 480 elems: full-wave butterfly
        float v1 = z000 + z001 + z010 + z011
                 + (hasb ? (z100 + z101 + z110 + z111) : 0.f);
        float v2 = z000 * z000 + z001 * z001 + z010 * z010 + z011 * z011
                 + (hasb ? (z100 * z100 + z101 * z101
                          + z110 * z110 + z111 * z111) : 0.f);
        #pragma unroll
        for (int m = 1; m <= 32; m <<= 1) {
            v1 += __shfl_xor(v1, m);
            v2 += __shfl_xor(v2, m);
        }
        mean = v1 * (1.f / 480.f);
        var  = v2 * (1.f / 480.f) - mean * mean;
        rstd = rsqrtf(var + 1e-5f);

        // normalize+relu -> h3; accumulate relu'd sums for IN4 stats
        // p(global in 480) = ((c2&1)*2 + j2)*120 + ((c1&1)*2 + j1)*30 + p1
        const int qb0 = (c1l >> 1) * 240;
        const int pb0 = (c1l & 1) * 60;
        float* hw = h3 + c3 * 480;
        float s4 = 0.f, q4 = 0.f;
        {
            float v;
            v = fmaxf((z000 - mean) * rstd, 0.f); hw[qb0 +       pb0 +      p16] = v; s4 += v; q4 += v * v;
            v = fmaxf((z001 - mean) * rstd, 0.f); hw[qb0 + 120 + pb0 +      p16] = v; s4 += v; q4 += v * v;
            v = fmaxf((z010 - mean) * rstd, 0.f); hw[qb0 +       pb0 + 30 + p16] = v; s4 += v; q4 += v * v;
            v = fmaxf((z011 - mean) * rstd, 0.f); hw[qb0 + 120 + pb0 + 30 + p16] = v; s4 += v; q4 += v * v;
            if (hasb) {
                v = fmaxf((z100 - mean) * rstd, 0.f); hw[qb0 +       pb0 +      p16 + 16] = v; s4 += v; q4 += v * v;
                v = fmaxf((z101 - mean) * rstd, 0.f); hw[qb0 + 120 + pb0 +      p16 + 16] = v; s4 += v; q4 += v * v;
                v = fmaxf((z110 - mean) * rstd, 0.f); hw[qb0 +       pb0 + 30 + p16 + 16] = v; s4 += v; q4 += v * v;
                v = fmaxf((z111 - mean) * rstd, 0.f); hw[qb0 + 120 + pb0 + 30 + p16 + 16] = v; s4 += v; q4 += v * v;
            }
        }
        #pragma unroll
        for (int m = 1; m <= 32; m <<= 1) {
            s4 += __shfl_xor(s4, m);
            q4 += __shfl_xor(q4, m);
        }
        if (l == 0) {
            // stage4 IN stats analytically:
            // x4[c, j*480+p] = h3[c,p]*w4[c*4+j] + b4[c*4+j]
            float sum4 = 0.f, sq4 = 0.f;
            #pragma unroll
            for (int j = 0; j < 4; ++j) {
                float ww = w4[c3 * 4 + j], bb = b4[c3 * 4 + j];
                sum4 += ww * s4 + 480.f * bb;
                sq4  += ww * ww * q4 + 2.f * ww * bb * s4 + 480.f * bb * bb;
            }
            float m4 = sum4 * (1.f / 1920.f);
            float var4 = sq4 * (1.f / 1920.f) - m4 * m4;
            m4s[c3] = m4; r4s[c3] = rsqrtf(var4 + 1e-5f);
        }
    }
    __syncthreads();

    // per-point: stage4 apply + stage5 einsum + tanh + emit + COUNT pairs
    int x0s[2], y0s[2], z0s[2];
    #pragma unroll
    for (int k = 0; k < 2; ++k) {
        int p = t + k * 1024;
        if (p >= NPT) break;
        int j = p / 480;
        int pp = p - j * 480;
        float a0e = b5[0], a1e = b5[1], a2e = b5[2];
        #pragma unroll
        for (int c = 0; c < 16; ++c) {
            float xv = h3[c * 480 + pp];
            float x4 = fmaf(xv, w4[c * 4 + j], b4[c * 4 + j]);
            float h  = fmaxf((x4 - m4s[c]) * r4s[c], 0.f);
            a0e = fmaf(w5[c],      h, a0e);
            a1e = fmaf(w5[16 + c], h, a1e);
            a2e = fmaf(w5[32 + c], h, a2e);
        }
        float px = tanhf(a0e) * 64.f + 63.5f;
        float py = tanhf(a1e) * 64.f + 63.5f;
        float pz = tanhf(a2e) * 64.f + 63.5f;
        float val = 1.f / (1.f + expf(-qval[p]));

        float4 pv; pv.x = px; pv.y = py; pv.z = pz; pv.w = val;
        pts[b * NPT + p] = pv;

        int x0 = (int)floorf(px), y0 = (int)floorf(py), z0 = (int)floorf(pz);
        x0s[k] = x0; y0s[k] = y0; z0s[k] = z0;
        int xlo = max(0, x0 - 3), xhi = min(127, x0 + 4);
        int ylo = max(0, y0 - 3), yhi = min(127, y0 + 4);
        int zlo = max(0, z0 - 3), zhi = min(127, z0 + 4);
        int pxl = xlo >> 4, pxh = xhi >> 4;
        int tyl = ylo >> 3, tyh = yhi >> 3;
        int tzl = zlo >> 3, tzh = zhi >> 3;
        for (int tz = tzl; tz <= tzh; ++tz)
            for (int ty = tyl; ty <= tyh; ++ty)
                for (int px2 = pxl; px2 <= pxh; ++px2)
                    atomicAdd(&cnt[(tz * 16 + ty) * 8 + px2], 1);
    }
    __syncthreads();

    // prefix-sum cnt -> rowptr (global rp) + fill cursors (off)
    if (t < 64) {
        int s = 0;
        for (int i = 0; i < 32; ++i) s += cnt[t * 32 + i];
        gsum[t] = s;
    }
    __syncthreads();
    if (t == 0) {
        int s = 0;
        for (int i = 0; i < 64; ++i) { int v = gsum[i]; gsum[i] = s; s += v; }
    }
    __syncthreads();
    if (t < 64) {
        int s = gsum[t];
        for (int i = 0; i < 32; ++i) {
            int u = t * 32 + i;
            rp[b * 2049 + u] = s;
            off[u] = s;
            s += cnt[u];
        }
        if (t == 63) rp[b * 2049 + 2048] = s;
    }
    __syncthreads();

    // fill CSR entries + compact active pairs
    #pragma unroll
    for (int k = 0; k < 2; ++k) {
        int p = t + k * 1024;
        if (p >= NPT) break;
        int x0 = x0s[k], y0 = y0s[k], z0 = z0s[k];
        int xlo = max(0, x0 - 3), xhi = min(127, x0 + 4);
        int ylo = max(0, y0 - 3), yhi = min(127, y0 + 4);
        int zlo = max(0, z0 - 3), zhi = min(127, z0 + 4);
        int pxl = xlo >> 4, pxh = xhi >> 4;
        int tyl = ylo >> 3, tyh = yhi >> 3;
        int tzl = zlo >> 3, tzh = zhi >> 3;
        for (int tz = tzl; tz <= tzh; ++tz)
            for (int ty = tyl; ty <= tyh; ++ty)
                for (int px2 = pxl; px2 <= pxh; ++px2) {
                    int pos = atomicAdd(&off[(tz * 16 + ty) * 8 + px2], 1);
                    ent[b * 16384 + pos] = p;
                }
    }
    for (int u = t; u < 2048; u += 1024) {
        if (cnt[u] > 0) {
            int pos = atomicAdd(&lcount, 1);
            list[b * 2048 + pos] = (b << 11) | u;
        }
    }
    __syncthreads();
    if (t == 0) bcount[b] = lcount;
}

// ---------------------------------------------------------------------------
// Tile kernel (R2/R4-proven structure): 1024 blocks x 512 threads, 34.5 KB
// LDS, grid-stride over concatenated active lists. Splat is now CSR-driven:
// only the ~dozen points touching this tile are read. Smooth z/y/x IN PLACE
// with per-column register rolling, divide, store 16x8x8.
// ---------------------------------------------------------------------------
__global__ __launch_bounds__(512, 8)
void tile_k(const float4* __restrict__ pts, const int* __restrict__ bcount,
            const int* __restrict__ list, const int* __restrict__ rp,
            const int* __restrict__ ent, float* __restrict__ out)
{
    __shared__ float2 raw[4312];
    __shared__ int pf[17];

    const int t = threadIdx.x;
    if (t < 16) pf[t + 1] = bcount[t];
    if (t == 0) pf[0] = 0;
    __syncthreads();
    if (t == 0) {
        int s = 0;
        #pragma unroll
        for (int i = 1; i <= 16; ++i) { s += pf[i]; pf[i] = s; }
    }
    __syncthreads();
    const int total = pf[16];

    for (int idx = blockIdx.x; idx < total; idx += gridDim.x) {
        int bb = 0;
        #pragma unroll 1
        for (; bb < 15; ++bb) if (idx < pf[bb + 1]) break;
        const int code = list[bb * 2048 + (idx - pf[bb])];
        const int u    = code & 2047;
        const int pb_  = code >> 11;
        const int Tx = (code & 7) * 16;
        const int Ty = ((code >> 3) & 15) * 8;
        const int Tz = ((code >> 7) & 15) * 8;
        const int base = rp[pb_ * 2049 + u];
        const int endp = rp[pb_ * 2049 + u + 1];
        float* ob = out + (((size_t)(pb_ * NVOX + Tz) * NVOX + Ty) * NVOX + Tx);

        {   // zero the LDS tile (float4 fill)
            float4* rz = (float4*)raw;
            for (int v = t; v < 2156; v += 512) rz[v] = make_float4(0.f, 0.f, 0.f, 0.f);
        }
        __syncthreads();

        // CSR splat: only this tile's points
        for (int e = base + t; e < endp; e += 512) {
            int p = ent[pb_ * 16384 + e];
            float4 pt = pts[pb_ * NPT + p];
            float x0f = floorf(pt.x), y0f = floorf(pt.y), z0f = floorf(pt.z);
            int x0 = (int)x0f, y0 = (int)y0f, z0 = (int)z0f;
            int lx0 = x0 - Tx + 3, ly0 = y0 - Ty + 3, lz0 = z0 - Tz + 3;
            float fx = pt.x - x0f, fy = pt.y - y0f, fz = pt.z - z0f;
            float val = pt.w;
            #pragma unroll
            for (int dz = 0; dz < 2; ++dz) {
                int zi = z0 + dz, lz = lz0 + dz;
                if ((unsigned)zi >= 128u || (unsigned)lz >= 14u) continue;
                float wz = dz ? fz : 1.f - fz;
                #pragma unroll
                for (int dy = 0; dy < 2; ++dy) {
                    int yi = y0 + dy, ly = ly0 + dy;
                    if ((unsigned)yi >= 128u || (unsigned)ly >= 14u) continue;
                    float wy = dy ? fy : 1.f - fy;
                    #pragma unroll
                    for (int dx = 0; dx < 2; ++dx) {
                        int xi = x0 + dx, lx = lx0 + dx;
                        if ((unsigned)xi >= 128u || (unsigned)lx >= 22u) continue;
                        float w = (dx ? fx : 1.f - fx) * wy * wz;
                        float2* cell = &raw[(lz * 14 + ly) * 22 + lx];
                        atomicAdd(&cell->x, w * val);
                        atomicAdd(&cell->y, w);
                    }
                }
            }
        }
        __syncthreads();

        // z-pass IN PLACE: column (ly,lx) = t, stride 308; 14 reads -> 8 out
        if (t < 308) {
            float2 w0 = raw[t],            w1_ = raw[t + 308],
                   w2_ = raw[t + 2 * 308], w3_ = raw[t + 3 * 308],
                   w4_ = raw[t + 4 * 308], w5_ = raw[t + 5 * 308],
                   w6_ = raw[t + 6 * 308];
            #pragma unroll
            for (int z = 0; z < 8; ++z) {
                float cm1, c0, cp1; coef(Tz + z, cm1, c0, cp1);
                float sx = (w0.x + w6_.x) + 3.f * (w1_.x + w5_.x)
                         + cm1 * w2_.x + c0 * w3_.x + cp1 * w4_.x;
                float sy = (w0.y + w6_.y) + 3.f * (w1_.y + w5_.y)
                         + cm1 * w2_.y + c0 * w3_.y + cp1 * w4_.y;
                float2 nxt = raw[t + ((z < 7) ? z + 7 : 7) * 308];
                raw[t + z * 308] = f2(sx * (1.f / 27.f), sy * (1.f / 27.f));
                w0 = w1_; w1_ = w2_; w2_ = w3_; w3_ = w4_; w4_ = w5_; w5_ = w6_; w6_ = nxt;
            }
        }
        __syncthreads();

        // y-pass IN PLACE: columns (z,lx), z<8, stride 22
        if (t < 176) {
            int z = t / 22, lx = t - z * 22;
            float2* base2 = &raw[z * 308 + lx];
            float2 w0 = base2[0],       w1_ = base2[22],
                   w2_ = base2[2 * 22], w3_ = base2[3 * 22],
                   w4_ = base2[4 * 22], w5_ = base2[5 * 22],
                   w6_ = base2[6 * 22];
            #pragma unroll
            for (int y = 0; y < 8; ++y) {
                float cm1, c0, cp1; coef(Ty + y, cm1, c0, cp1);
                float sx = (w0.x + w6_.x) + 3.f * (w1_.x + w5_.x)
                         + cm1 * w2_.x + c0 * w3_.x + cp1 * w4_.x;
                float sy = (w0.y + w6_.y) + 3.f * (w1_.y + w5_.y)
                         + cm1 * w2_.y + c0 * w3_.y + cp1 * w4_.y;
                float2 nxt = base2[((y < 7) ? y + 7 : 7) * 22];
                base2[y * 22] = f2(sx * (1.f / 27.f), sy * (1.f / 27.f));
                w0 = w1_; w1_ = w2_; w2_ = w3_; w3_ = w4_; w4_ = w5_; w5_ = w6_; w6_ = nxt;
            }
        }
        __syncthreads();

        // x-pass + division: 2 threads per (z,y) row, 8 outputs each
        if (t < 128) {
            int row = t >> 1, hx = t & 1;
            int z = row >> 3, y = row & 7;
            const float2* a = &raw[z * 308 + y * 22 + hx * 8];
            float2 w0 = a[0], w1_ = a[1], w2_ = a[2], w3_ = a[3],
                   w4_ = a[4], w5_ = a[5], w6_ = a[6];
            float res[8];
            #pragma unroll
            for (int i = 0; i < 8; ++i) {
                int x = hx * 8 + i;
                float cm1, c0, cp1; coef(Tx + x, cm1, c0, cp1);
                float sx = (w0.x + w6_.x) + 3.f * (w1_.x + w5_.x)
                         + cm1 * w2_.x + c0 * w3_.x + cp1 * w4_.x;
                float sy = (w0.y + w6_.y) + 3.f * (w1_.y + w5_.y)
                         + cm1 * w2_.y + c0 * w3_.y + cp1 * w4_.y;
                res[i] = (sx * (1.f / 27.f)) / (sy * (1.f / 27.f) + 0.001f);
                float2 nxt = a[(i < 7) ? i + 7 : 13];
                w0 = w1_; w1_ = w2_; w2_ = w3_; w3_ = w4_; w4_ = w5_; w5_ = w6_; w6_ = nxt;
            }
            float* orow = &ob[((size_t)z * NVOX + y) * NVOX + hx * 8];
            *(float4*)&orow[0] = make_float4(res[0], res[1], res[2], res[3]);
            *(float4*)&orow[4] = make_float4(res[4], res[5], res[6], res[7]);
        }
        __syncthreads();   // raw re-zeroed next iteration
    }
}

// ---------------------------------------------------------------------------
extern "C" void kernel_launch(void* const* d_in, const int* in_sizes, int n_in,
                              void* d_out, int out_size, void* d_ws, size_t ws_size,
                              hipStream_t stream)
{
    const float* q    = (const float*)d_in[0];
    const float* qval = (const float*)d_in[1];
    const float* w1   = (const float*)d_in[2];
    const float* b1   = (const float*)d_in[3];
    const float* w2   = (const float*)d_in[4];
    const float* b2   = (const float*)d_in[5];
    const float* w3   = (const float*)d_in[6];
    const float* b3   = (const float*)d_in[7];
    const float* w4   = (const float*)d_in[8];
    const float* b4   = (const float*)d_in[9];
    const float* w5   = (const float*)d_in[10];
    const float* b5   = (const float*)d_in[11];
    float* out = (float*)d_out;

    // ws layout:
    //   [0,        64)      bcount (16 ints, padded)
    //   [64,       131136)  list   (16 x 2048 ints)
    //   [131136,   262272)  rp     (16 x 2049 ints, CSR row pointers)
    //   [262272,   1310848) ent    (16 x 16384 ints, CSR entries)
    //   [1310848,  1802368) pts    (16 x 1920 float4)
    int*    bcount = (int*)d_ws;
    int*    list   = (int*)((char*)d_ws + 64);
    int*    rp     = (int*)((char*)d_ws + 131136);
    int*    ent    = (int*)((char*)d_ws + 262272);
    float4* pts    = (float4*)((char*)d_ws + 1310848);

    tail_zero_k<<<512, 1024, 0, stream>>>(q, w1, b1, qval, w2, b2, w3, b3,
                                          w4, b4, w5, b5, pts, bcount, list,
                                          rp, ent, (float4*)out);

    tile_k<<<1024, 512, 0, stream>>>(pts, bcount, list, rp, ent, out);
}